// Round 16
// baseline (239.899 us; speedup 1.0000x reference)
//
#include <hip/hip_runtime.h>
#include <hip/hip_bf16.h>

// ---------------------------------------------------------------------------
// B=8, C=128, H=W=128, hw=16384, heads=8.
//  packw/packcw (once): weights -> f16-pair packed
//  K1 gemm_t: tpk = f16-pair-packed(pos_w @ x + pos_b) (MFMA f16)
//             epilogue via LDS transpose -> coalesced uint4 stores;
//             also emits xpk (x as f16 ch-pairs) from its LDS stage.
//  K2 dualconv(xpk): conv3+conv5 -> vy rows 128..255   (v_dot2, 16-row tile)
//  K3 dualconv(tpk): conv3+conv5 -> q,k,v bf16
//  K4 gram: S, |q|^2, |k|^2 per (b,h) via 3 MFMAs/iter (MFMA bf16)
//  K5 attn_fold: softmax fold -> wallpk (bf16 pairs)
//  K6 gemm_out: out f32 = wallpk @ vy (N-tile 64)      (MFMA bf16)
// r16 = r15 with the store-loop coverage bug fixed: each thread stores
// 4 uint4 per pass (cols qd*16..qd*16+15), 12 uint4 total — full 192x64
// tile (r15 wrote only 1/4 of it -> absmax 0.188).
// ---------------------------------------------------------------------------

#define HW 16384
#define HH 128
#define WW 128

typedef __attribute__((ext_vector_type(8))) short bf16x8;
typedef __attribute__((ext_vector_type(8))) _Float16 f16x8;
typedef __attribute__((ext_vector_type(4))) float f32x4;
typedef __attribute__((ext_vector_type(4))) unsigned short us4;
typedef __fp16 fp16x2 __attribute__((ext_vector_type(2)));

__device__ inline unsigned short f2bf(float f) {
    unsigned u = __float_as_uint(f);
    return (unsigned short)((u + 0x7FFFu + ((u >> 16) & 1u)) >> 16);
}
__device__ inline unsigned packbf(float lo, float hi) {
    return (unsigned)f2bf(lo) | ((unsigned)f2bf(hi) << 16);
}
__device__ inline unsigned short f2h(float f) {
    _Float16 h = (_Float16)f;
    return __builtin_bit_cast(unsigned short, h);
}
__device__ inline unsigned packh(float lo, float hi) {
    return (unsigned)f2h(lo) | ((unsigned)f2h(hi) << 16);
}
// 1-instr packed f32->f16 (RTZ): v_cvt_pkrtz_f16_f32
__device__ inline unsigned packh2(float lo, float hi) {
    fp16x2 h = __builtin_amdgcn_cvt_pkrtz(lo, hi);
    return __builtin_bit_cast(unsigned, h);
}

// D = a.lo*w.lo + a.hi*w.hi + c ; w block-uniform (SGPR ok on VOP3P).
__device__ inline float dot2acc(unsigned a, unsigned w, float c) {
    float d;
    asm("v_dot2_f32_f16 %0, %1, %2, %3" : "=v"(d) : "v"(a), "s"(w), "v"(c));
    return d;
}

__global__ void zerok(float* p, int n) {
    int i = blockIdx.x * 256 + threadIdx.x;
    if (i < n) p[i] = 0.f;
}

// pack pos_w [384][128] f32 -> poswpk [384][64] u32 (f16 pairs along k)
__global__ __launch_bounds__(256) void packw(const float* __restrict__ w,
                                             unsigned* __restrict__ wpk) {
    int id = blockIdx.x * 256 + threadIdx.x;
    if (id >= 384 * 64) return;
    int m = id >> 6, kp = id & 63;
    wpk[id] = packh(w[m * 128 + 2 * kp], w[m * 128 + 2 * kp + 1]);
}

// pack conv weights: channel-pair f16 per tap.
__global__ __launch_bounds__(256) void packcw(
    const float* __restrict__ qd3, const float* __restrict__ qd5,
    const float* __restrict__ d3, const float* __restrict__ d5,
    unsigned* __restrict__ o) {
    int id = blockIdx.x * 256 + threadIdx.x;
    if (id < 192 * 9) {
        int g = id / 9, tp = id % 9;
        o[id] = packh(qd3[(g * 2) * 9 + tp], qd3[(g * 2 + 1) * 9 + tp]);
    } else if (id < 192 * 9 + 192 * 25) {
        int r = id - 192 * 9; int g = r / 25, tp = r % 25;
        o[id] = packh(qd5[(g * 2) * 25 + tp], qd5[(g * 2 + 1) * 25 + tp]);
    } else if (id < 192 * 9 + 192 * 25 + 64 * 9) {
        int r = id - 192 * 9 - 192 * 25; int g = r / 9, tp = r % 9;
        o[id] = packh(d3[(g * 2) * 9 + tp], d3[(g * 2 + 1) * 9 + tp]);
    } else if (id < 192 * 9 + 192 * 25 + 64 * 9 + 64 * 25) {
        int r = id - 192 * 9 - 192 * 25 - 64 * 9; int g = r / 25, tp = r % 25;
        o[id] = packh(d5[(g * 2) * 25 + tp], d5[(g * 2 + 1) * 25 + tp]);
    }
}

// ---------------- K1: tpk = f16-pair-packed(pos_w @ x + b); LDS-transposed
// epilogue for coalesced stores; also emits xpk.
__global__ __launch_bounds__(256) void gemm_t(
    const unsigned* __restrict__ wpk,   // [384][64] u32 f16 k-pairs (L2)
    const float* __restrict__ x,        // [NB][128][HW] f32
    const float* __restrict__ posb,     // [384]
    unsigned* __restrict__ tpk,         // [NB][192][HW] u32 f16 ch-pairs
    unsigned* __restrict__ xpk)         // [NB][64][HW] u32 f16 ch-pairs
{
    int b = blockIdx.z;
    int n0 = blockIdx.x * 64;
    const float* xb = x + (long)b * 128 * HW;
    unsigned* tb = tpk + (long)b * 192 * HW;
    __shared__ unsigned S[192 * 68];    // 52.2KB; first 64*65 words alias Bs
    unsigned (*Bs)[65] = (unsigned (*)[65])S;
    int tid = threadIdx.x;
    {   // stage 64 n x 64 kp, packing f32 ch-pairs -> f16 pairs; dump to xpk
        int kp = tid >> 2, nq = tid & 3;
        const float* s0 = xb + (long)(2 * kp) * HW + n0 + nq * 16;
        const float* s1 = s0 + HW;
        unsigned* xo = xpk + (long)b * 64 * HW + (long)kp * HW + n0 + nq * 16;
        int nb_ = nq * 16;
        #pragma unroll
        for (int q4 = 0; q4 < 4; ++q4) {
            float4 lo = *(const float4*)(s0 + q4 * 4);
            float4 hi = *(const float4*)(s1 + q4 * 4);
            uint4 o;
            o.x = packh2(lo.x, hi.x);
            o.y = packh2(lo.y, hi.y);
            o.z = packh2(lo.z, hi.z);
            o.w = packh2(lo.w, hi.w);
            Bs[nb_ + q4 * 4 + 0][kp] = o.x;
            Bs[nb_ + q4 * 4 + 1][kp] = o.y;
            Bs[nb_ + q4 * 4 + 2][kp] = o.z;
            Bs[nb_ + q4 * 4 + 3][kp] = o.w;
            *(uint4*)(xo + q4 * 4) = o;
        }
    }
    __syncthreads();
    int w = tid >> 6, l = tid & 63;
    int lr = l & 15, lg = l >> 4;
    f32x4 acc[6][4] = {};
    #pragma unroll
    for (int kk = 0; kk < 4; ++kk) {
        f16x8 af[6];
        #pragma unroll
        for (int mt = 0; mt < 6; ++mt) {
            int m = (w * 6 + mt) * 16 + lr;
            af[mt] = *(const f16x8*)(wpk + (long)m * 64 + kk * 16 + lg * 4);
        }
        #pragma unroll
        for (int ns = 0; ns < 4; ++ns) {
            f16x8 bf = *(const f16x8*)(&Bs[ns * 16 + lr][kk * 16 + lg * 4]);
            #pragma unroll
            for (int mt = 0; mt < 6; ++mt)
                acc[mt][ns] = __builtin_amdgcn_mfma_f32_16x16x32_f16(
                    af[mt], bf, acc[mt][ns], 0, 0, 0);
        }
    }
    __syncthreads();   // all Bs reads done; S is reused for the output tile
    #pragma unroll
    for (int mt = 0; mt < 6; ++mt) {
        int m0 = w * 96 + mt * 16 + lg * 4;
        float b0v = posb[m0], b1v = posb[m0 + 1], b2v = posb[m0 + 2], b3v = posb[m0 + 3];
        int p0 = m0 >> 1;               // planes p0, p0+1
        #pragma unroll
        for (int ns = 0; ns < 4; ++ns) {
            int col = ns * 16 + lr;
            S[p0 * 68 + col]       = packh2(acc[mt][ns][0] + b0v, acc[mt][ns][1] + b1v);
            S[(p0 + 1) * 68 + col] = packh2(acc[mt][ns][2] + b2v, acc[mt][ns][3] + b3v);
        }
    }
    __syncthreads();
    {   // coalesced store: 3 passes, 4 uint4/thread/pass (full 192x64 tile)
        int row0 = tid >> 2, qd = tid & 3;
        #pragma unroll
        for (int pass = 0; pass < 3; ++pass) {
            int row = pass * 64 + row0;
            #pragma unroll
            for (int j4 = 0; j4 < 4; ++j4) {
                uint4 v = *(const uint4*)&S[row * 68 + qd * 16 + j4 * 4];
                *(uint4*)(tb + (long)row * HW + n0 + qd * 16 + j4 * 4) = v;
            }
        }
    }
}

// ---------------- merged conv3+conv5 via f16 dot2; src pair-packed u32 planes.
// 16 output rows per block, 8 px per thread, 2 groups per block.
__global__ __launch_bounds__(256) void dualconv(
    const unsigned* __restrict__ src, int srcP,   // [NB][srcP][HW] u32
    const unsigned* __restrict__ w3pk, const float* __restrict__ b3,
    const unsigned* __restrict__ w5pk, const float* __restrict__ b5,
    int s3, unsigned short* __restrict__ r3a, long st3a,
    unsigned short* __restrict__ r3b, long st3b,
    int s5, unsigned short* __restrict__ r5a, long st5a,
    unsigned short* __restrict__ r5b, long st5b)
{
    int gp = blockIdx.y, b = blockIdx.z, y0 = blockIdx.x * 16;
    __shared__ __align__(16) unsigned tile[2][20][132];
    int tid = threadIdx.x;
    const unsigned* sU = src + ((long)b * srcP + 2 * gp) * HW;
    const int TOT = 2 * 20 * 132;       // 5280
    for (int idx = tid; idx < TOT; idx += 256) {
        int gi = idx / (20 * 132);
        int rem = idx - gi * (20 * 132);
        int r = rem / 132, ci = rem - r * 132;
        int row = y0 + r - 2, col = ci - 2;
        unsigned u = 0;
        if ((unsigned)row < (unsigned)HH && (unsigned)col < (unsigned)WW)
            u = sU[(long)gi * HW + row * WW + col];
        tile[gi][r][ci] = u;
    }
    __syncthreads();
    int xq = tid & 15, yy = tid >> 4;   // 16 col-groups x 16 rows
    int x0 = xq * 8;
    float a3[2][8], a5[2][8];
    #pragma unroll
    for (int gi = 0; gi < 2; ++gi) {
        int g = 2 * gp + gi;
        #pragma unroll
        for (int j = 0; j < 8; ++j) { a3[gi][j] = b3[g]; a5[gi][j] = b5[g]; }
        unsigned w5v[25], w3v[9];
        #pragma unroll
        for (int i = 0; i < 25; ++i) w5v[i] = w5pk[g * 25 + i];
        #pragma unroll
        for (int i = 0; i < 9; ++i) w3v[i] = w3pk[g * 9 + i];
        #pragma unroll
        for (int r = 0; r < 5; ++r) {
            const unsigned* p = &tile[gi][yy + r][x0];
            unsigned win[12];
            *(f32x4*)win = *(const f32x4*)p;
            *(f32x4*)(win + 4) = *(const f32x4*)(p + 4);
            *(f32x4*)(win + 8) = *(const f32x4*)(p + 8);
            #pragma unroll
            for (int dx = 0; dx < 5; ++dx)
                #pragma unroll
                for (int j = 0; j < 8; ++j)
                    a5[gi][j] = dot2acc(win[j + dx], w5v[r * 5 + dx], a5[gi][j]);
            if (r >= 1 && r <= 3) {
                #pragma unroll
                for (int dx = 0; dx < 3; ++dx)
                    #pragma unroll
                    for (int j = 0; j < 8; ++j)
                        a3[gi][j] = dot2acc(win[j + dx + 1], w3v[(r - 1) * 3 + dx], a3[gi][j]);
            }
        }
    }
    long prow = (long)(y0 + yy) * WW + x0;
    #pragma unroll
    for (int gi = 0; gi < 2; ++gi) {
        int g = 2 * gp + gi;
        uint4 v3, v5;
        v3.x = packbf(a3[gi][0], a3[gi][1]);
        v3.y = packbf(a3[gi][2], a3[gi][3]);
        v3.z = packbf(a3[gi][4], a3[gi][5]);
        v3.w = packbf(a3[gi][6], a3[gi][7]);
        v5.x = packbf(a5[gi][0], a5[gi][1]);
        v5.y = packbf(a5[gi][2], a5[gi][3]);
        v5.z = packbf(a5[gi][4], a5[gi][5]);
        v5.w = packbf(a5[gi][6], a5[gi][7]);
        unsigned short* d3 = (g < s3) ? r3a + (long)b * st3a + (long)g * HW
                                      : r3b + (long)b * st3b + (long)(g - s3) * HW;
        unsigned short* d5 = (g < s5) ? r5a + (long)b * st5a + (long)g * HW
                                      : r5b + (long)b * st5b + (long)(g - s5) * HW;
        *(uint4*)(d3 + prow) = v3;
        *(uint4*)(d5 + prow) = v5;
    }
}

// ---------------- Gram + norms, 3 MFMAs per iter (S, q.q^T diag, k.k^T diag)
__global__ __launch_bounds__(64) void gram_mfma(
    const unsigned short* __restrict__ q,  // [NB][128][HW] bf16
    const unsigned short* __restrict__ k,
    float* __restrict__ gbuf)              // [NB*8][288]
{
    int bh = blockIdx.x, chunk = blockIdx.y;
    int b = bh >> 3, h = bh & 7;
    int l = threadIdx.x;
    int r = l & 15, koff = (l >> 4) * 8;
    const unsigned short* qrow = q + ((long)b * 128 + h * 16 + r) * HW;
    const unsigned short* krow = k + ((long)b * 128 + h * 16 + r) * HW;
    f32x4 accS = {0.f, 0.f, 0.f, 0.f};
    f32x4 accQ = {0.f, 0.f, 0.f, 0.f};
    f32x4 accK = {0.f, 0.f, 0.f, 0.f};
    int n0 = chunk * 256;
    for (int n = n0; n < n0 + 256; n += 32) {
        bf16x8 af = *(const bf16x8*)(qrow + n + koff);
        bf16x8 bf = *(const bf16x8*)(krow + n + koff);
        accS = __builtin_amdgcn_mfma_f32_16x16x32_bf16(af, bf, accS, 0, 0, 0);
        accQ = __builtin_amdgcn_mfma_f32_16x16x32_bf16(af, af, accQ, 0, 0, 0);
        accK = __builtin_amdgcn_mfma_f32_16x16x32_bf16(bf, bf, accK, 0, 0, 0);
    }
    float* gb = gbuf + bh * 288;
    #pragma unroll
    for (int reg = 0; reg < 4; ++reg) {
        int row = (l >> 4) * 4 + reg;
        atomicAdd(&gb[row * 16 + r], accS[reg]);
        if (row == r) {
            atomicAdd(&gb[256 + r], accQ[reg]);
            atomicAdd(&gb[272 + r], accK[reg]);
        }
    }
}

// ---------------- softmax + fold into packed bf16 proj weights
__global__ __launch_bounds__(256) void attn_fold(
    const float* __restrict__ gbuf, const float* __restrict__ temp,
    const float* __restrict__ projw,     // [128][256]
    unsigned* __restrict__ wallpk)       // [NB][128][128] u32 bf16-pairs
{
    int bh = blockIdx.x;
    int b = bh >> 3, h = bh & 7;
    const float* gb = gbuf + bh * 288;
    __shared__ float logit[16][16];
    __shared__ float A[16][16];
    int tid = threadIdx.x;
    int d = tid >> 4, e = tid & 15;
    {
        float nq = fmaxf(sqrtf(gb[256 + d]), 1e-12f);
        float nk = fmaxf(sqrtf(gb[272 + e]), 1e-12f);
        logit[d][e] = gb[d * 16 + e] / (nq * nk) * temp[h];
    }
    __syncthreads();
    float m = -1e30f;
    #pragma unroll
    for (int j = 0; j < 16; ++j) m = fmaxf(m, logit[d][j]);
    float ex = expf(logit[d][e] - m);
    A[d][e] = ex;
    __syncthreads();
    float sum = 0.f;
    #pragma unroll
    for (int j = 0; j < 16; ++j) sum += A[d][j];
    __syncthreads();
    A[d][e] = ex / sum;
    __syncthreads();
    int ep = tid & 7, co0 = tid >> 3;
    for (int co = co0; co < 128; co += 32) {
        float lo = 0.f, hi = 0.f;
        #pragma unroll
        for (int dd = 0; dd < 16; ++dd) {
            float pw = projw[co * 256 + h * 16 + dd];
            lo += pw * A[dd][2 * ep];
            hi += pw * A[dd][2 * ep + 1];
        }
        wallpk[((long)b * 128 + co) * 128 + h * 8 + ep] = packbf(lo, hi);
    }
    if (h == 0) {
        for (int idx = tid; idx < 128 * 64; idx += 256) {
            int co = idx >> 6, cp = idx & 63;
            wallpk[((long)b * 128 + co) * 128 + 64 + cp] =
                packbf(projw[co * 256 + 128 + 2 * cp], projw[co * 256 + 129 + 2 * cp]);
        }
    }
}

// ---------------- K6: out f32 = wallpk @ vy  (M=128, K=256, N-tile 64)
__global__ __launch_bounds__(256) void gemm_out(
    const unsigned* __restrict__ wpk,       // [NB][128][128] u32 (L2)
    const unsigned short* __restrict__ vy,  // [NB][256][HW] bf16
    float* __restrict__ out)                // [NB][128][HW]
{
    int b = blockIdx.z;
    int n0 = blockIdx.x * 64;
    const unsigned* wb = wpk + (long)b * 128 * 128;
    const unsigned short* vyb = vy + (long)b * 256 * HW;
    float* ob = out + (long)b * 128 * HW;
    __shared__ unsigned Bs[64][129];
    int tid = threadIdx.x;
    {   // stage 64 n x 128 kp
        int kp = tid >> 1, nh = (tid & 1) * 32;
        const unsigned short* s0 = vyb + (long)(2 * kp) * HW + n0 + nh;
        const unsigned short* s1 = s0 + HW;
        #pragma unroll
        for (int q4 = 0; q4 < 4; ++q4) {
            us4 lo0 = *(const us4*)(s0 + q4 * 8);
            us4 lo1 = *(const us4*)(s0 + q4 * 8 + 4);
            us4 hi0 = *(const us4*)(s1 + q4 * 8);
            us4 hi1 = *(const us4*)(s1 + q4 * 8 + 4);
            #pragma unroll
            for (int j = 0; j < 4; ++j) {
                Bs[nh + q4 * 8 + j][kp]     = (unsigned)lo0[j] | ((unsigned)hi0[j] << 16);
                Bs[nh + q4 * 8 + 4 + j][kp] = (unsigned)lo1[j] | ((unsigned)hi1[j] << 16);
            }
        }
    }
    __syncthreads();
    int w = tid >> 6, l = tid & 63;
    int lr = l & 15, lg = l >> 4;
    f32x4 acc[2][4] = {};
    #pragma unroll
    for (int kk = 0; kk < 8; ++kk) {
        bf16x8 af[2];
        #pragma unroll
        for (int i = 0; i < 2; ++i) {
            int m = (w * 2 + i) * 16 + lr;
            af[i] = *(const bf16x8*)(wb + (long)m * 128 + kk * 16 + lg * 4);
        }
        #pragma unroll
        for (int ns = 0; ns < 4; ++ns) {
            bf16x8 bf = *(const bf16x8*)(&Bs[ns * 16 + lr][kk * 16 + lg * 4]);
            #pragma unroll
            for (int i = 0; i < 2; ++i)
                acc[i][ns] = __builtin_amdgcn_mfma_f32_16x16x32_bf16(
                    af[i], bf, acc[i][ns], 0, 0, 0);
        }
    }
    #pragma unroll
    for (int i = 0; i < 2; ++i)
        #pragma unroll
        for (int ns = 0; ns < 4; ++ns)
            #pragma unroll
            for (int reg = 0; reg < 4; ++reg) {
                int m = (w * 2 + i) * 16 + lg * 4 + reg;
                ob[(long)m * HW + n0 + ns * 16 + lr] = acc[i][ns][reg];
            }
}

extern "C" void kernel_launch(void* const* d_in, const int* in_sizes, int n_in,
                              void* d_out, int out_size, void* d_ws, size_t ws_size,
                              hipStream_t stream) {
    const float* x      = (const float*)d_in[0];
    const float* pos_w  = (const float*)d_in[1];
    const float* pos_b  = (const float*)d_in[2];
    const float* qd3_w  = (const float*)d_in[3];
    const float* qd3_b  = (const float*)d_in[4];
    const float* qd5_w  = (const float*)d_in[5];
    const float* qd5_b  = (const float*)d_in[6];
    const float* temp   = (const float*)d_in[7];
    const float* d3_w   = (const float*)d_in[8];
    const float* d3_b   = (const float*)d_in[9];
    const float* d5_w   = (const float*)d_in[10];
    const float* d5_b   = (const float*)d_in[11];
    const float* proj_w = (const float*)d_in[12];
    float* out = (float*)d_out;

    // per-batch: tpk 12.58MB + (xpk|qb) 4.19 + kb 4.19 + vy 8.39 + wallpk 64K
    size_t perb = (size_t)HW * 1792 + 65536;
    size_t fixedb = 64UL * 288 * 4 + 384UL * 64 * 4 + 8704UL * 4;
    int NB = 8;
    while (NB > 1 && (size_t)NB * perb + fixedb > ws_size) NB >>= 1;

    char* base = (char*)d_ws;
    unsigned* tpk      = (unsigned*)base;       base += (size_t)NB * 192 * HW * 4;
    unsigned* xpk      = (unsigned*)base;                  // region A (aliased)
    unsigned short* qb = (unsigned short*)base; base += (size_t)NB * 128 * HW * 2;
    unsigned short* kb = (unsigned short*)base; base += (size_t)NB * 128 * HW * 2;
    unsigned short* vy = (unsigned short*)base; base += (size_t)NB * 256 * HW * 2;
    unsigned* wallpk   = (unsigned*)base;       base += (size_t)NB * 128 * 128 * 4;
    float* gram        = (float*)base;          base += 64UL * 288 * 4;
    unsigned* poswpk   = (unsigned*)base;       base += 384UL * 64 * 4;
    unsigned* cwpk     = (unsigned*)base;
    unsigned* qd3pk = cwpk;
    unsigned* qd5pk = cwpk + 192 * 9;
    unsigned* d3pk  = cwpk + 192 * 9 + 192 * 25;
    unsigned* d5pk  = cwpk + 192 * 9 + 192 * 25 + 64 * 9;

    packw<<<(384 * 64 + 255) / 256, 256, 0, stream>>>(pos_w, poswpk);
    packcw<<<(8704 + 255) / 256, 256, 0, stream>>>(qd3_w, qd5_w, d3_w, d5_w, cwpk);

    for (int b0 = 0; b0 < 8; b0 += NB) {
        const float* xb = x + (long)b0 * 128 * HW;
        float* outb = out + (long)b0 * 128 * HW;

        // t (pair-packed) = pos_w @ x + b ; also emits xpk (into qb region)
        gemm_t<<<dim3(HW / 64, 1, NB), 256, 0, stream>>>(poswpk, xb, pos_b, tpk, xpk);

        // convs on x (xpk): conv3 -> vy rows 128..191 ; conv5 -> rows 192..255
        // (must run BEFORE dualconv(t) overwrites the xpk/qb region)
        dualconv<<<dim3(8, 32, NB), 256, 0, stream>>>(
            xpk, 64, d3pk, d3_b, d5pk, d5_b,
            64, vy + 128L * HW, 256L * HW, vy + 128L * HW, 256L * HW,
            64, vy + 192L * HW, 256L * HW, vy + 192L * HW, 256L * HW);

        // convs on t: conv3: g<128 -> q(qb) ; g>=128 -> k rows 0..63
        //             conv5: g<64 -> k rows 64..127 ; g>=64 -> vy rows 0..127
        dualconv<<<dim3(8, 96, NB), 256, 0, stream>>>(
            tpk, 192, qd3pk, qd3_b, qd5pk, qd5_b,
            128, qb, 128L * HW, kb, 128L * HW,
            64, kb + 64L * HW, 128L * HW, vy, 256L * HW);

        zerok<<<(64 * 288 + 255) / 256, 256, 0, stream>>>(gram, 64 * 288);
        gram_mfma<<<dim3(NB * 8, 64), 64, 0, stream>>>(qb, kb, gram);
        attn_fold<<<NB * 8, 256, 0, stream>>>(gram, temp, proj_w, wallpk);

        gemm_out<<<dim3(HW / 64, 1, NB), 256, 0, stream>>>(wallpk, vy, outb);
    }
}

// Round 17
// 219.813 us; speedup vs baseline: 1.0914x; 1.0914x over previous
//
#include <hip/hip_runtime.h>
#include <hip/hip_bf16.h>

// ---------------------------------------------------------------------------
// B=8, C=128, H=W=128, hw=16384, heads=8.
//  packw/packcw (once): weights -> f16-pair packed
//  K1 gemm_t: tpk = f16-pair-packed(pos_w @ x + pos_b) (MFMA f16)
//             512-thread block, 8 waves x 3 m-tiles: ONE stage per strip,
//             acc[3][4]=48 VGPR -> high occupancy (r17). Scatter epilogue
//             (r13-proven; r15/r16 LDS-transpose regressed). Emits xpk too.
//  K2 dualconv(xpk): conv3+conv5 -> vy rows 128..255   (v_dot2, 16-row tile)
//  K3 dualconv(tpk): conv3+conv5 -> q,k,v bf16
//  K4 gram: S, |q|^2, |k|^2 per (b,h) via 3 MFMAs/iter (MFMA bf16)
//  K5 attn_fold: softmax fold -> wallpk (bf16 pairs)
//  K6 gemm_out: out f32 = wallpk @ vy (N-tile 64)      (MFMA bf16)
// gemm_t history: latency-bound at every config (all pipes <25%); r14
// cross-block M-split duplicated staging (regressed), r16 LDS-transpose
// halved occupancy (regressed). r17 = within-block wave-split: same single
// stage, 2x waves, half the acc regs.
// ---------------------------------------------------------------------------

#define HW 16384
#define HH 128
#define WW 128

typedef __attribute__((ext_vector_type(8))) short bf16x8;
typedef __attribute__((ext_vector_type(8))) _Float16 f16x8;
typedef __attribute__((ext_vector_type(4))) float f32x4;
typedef __attribute__((ext_vector_type(4))) unsigned short us4;
typedef __fp16 fp16x2 __attribute__((ext_vector_type(2)));

__device__ inline unsigned short f2bf(float f) {
    unsigned u = __float_as_uint(f);
    return (unsigned short)((u + 0x7FFFu + ((u >> 16) & 1u)) >> 16);
}
__device__ inline unsigned packbf(float lo, float hi) {
    return (unsigned)f2bf(lo) | ((unsigned)f2bf(hi) << 16);
}
__device__ inline unsigned short f2h(float f) {
    _Float16 h = (_Float16)f;
    return __builtin_bit_cast(unsigned short, h);
}
__device__ inline unsigned packh(float lo, float hi) {
    return (unsigned)f2h(lo) | ((unsigned)f2h(hi) << 16);
}
// 1-instr packed f32->f16 (RTZ): v_cvt_pkrtz_f16_f32
__device__ inline unsigned packh2(float lo, float hi) {
    fp16x2 h = __builtin_amdgcn_cvt_pkrtz(lo, hi);
    return __builtin_bit_cast(unsigned, h);
}

// D = a.lo*w.lo + a.hi*w.hi + c ; w block-uniform (SGPR ok on VOP3P).
__device__ inline float dot2acc(unsigned a, unsigned w, float c) {
    float d;
    asm("v_dot2_f32_f16 %0, %1, %2, %3" : "=v"(d) : "v"(a), "s"(w), "v"(c));
    return d;
}

__global__ void zerok(float* p, int n) {
    int i = blockIdx.x * 256 + threadIdx.x;
    if (i < n) p[i] = 0.f;
}

// pack pos_w [384][128] f32 -> poswpk [384][64] u32 (f16 pairs along k)
__global__ __launch_bounds__(256) void packw(const float* __restrict__ w,
                                             unsigned* __restrict__ wpk) {
    int id = blockIdx.x * 256 + threadIdx.x;
    if (id >= 384 * 64) return;
    int m = id >> 6, kp = id & 63;
    wpk[id] = packh(w[m * 128 + 2 * kp], w[m * 128 + 2 * kp + 1]);
}

// pack conv weights: channel-pair f16 per tap.
__global__ __launch_bounds__(256) void packcw(
    const float* __restrict__ qd3, const float* __restrict__ qd5,
    const float* __restrict__ d3, const float* __restrict__ d5,
    unsigned* __restrict__ o) {
    int id = blockIdx.x * 256 + threadIdx.x;
    if (id < 192 * 9) {
        int g = id / 9, tp = id % 9;
        o[id] = packh(qd3[(g * 2) * 9 + tp], qd3[(g * 2 + 1) * 9 + tp]);
    } else if (id < 192 * 9 + 192 * 25) {
        int r = id - 192 * 9; int g = r / 25, tp = r % 25;
        o[id] = packh(qd5[(g * 2) * 25 + tp], qd5[(g * 2 + 1) * 25 + tp]);
    } else if (id < 192 * 9 + 192 * 25 + 64 * 9) {
        int r = id - 192 * 9 - 192 * 25; int g = r / 9, tp = r % 9;
        o[id] = packh(d3[(g * 2) * 9 + tp], d3[(g * 2 + 1) * 9 + tp]);
    } else if (id < 192 * 9 + 192 * 25 + 64 * 9 + 64 * 25) {
        int r = id - 192 * 9 - 192 * 25 - 64 * 9; int g = r / 25, tp = r % 25;
        o[id] = packh(d5[(g * 2) * 25 + tp], d5[(g * 2 + 1) * 25 + tp]);
    }
}

// ---------------- K1: tpk = f16-pair-packed(pos_w @ x + b); 512 threads,
// 8 waves x 3 m-tiles; single stage; scatter epilogue; emits xpk.
__global__ __launch_bounds__(512) void gemm_t(
    const unsigned* __restrict__ wpk,   // [384][64] u32 f16 k-pairs (L2)
    const float* __restrict__ x,        // [NB][128][HW] f32
    const float* __restrict__ posb,     // [384]
    unsigned* __restrict__ tpk,         // [NB][192][HW] u32 f16 ch-pairs
    unsigned* __restrict__ xpk)         // [NB][64][HW] u32 f16 ch-pairs
{
    int b = blockIdx.z;
    int n0 = blockIdx.x * 64;
    const float* xb = x + (long)b * 128 * HW;
    unsigned* tb = tpk + (long)b * 192 * HW;
    __shared__ unsigned Bs[64][65];     // [n][kp], 16.6KB
    int tid = threadIdx.x;
    {   // stage 64 n x 64 kp: 512 threads, kp=tid>>3, 8 cols each
        int kp = tid >> 3, part = tid & 7;
        const float* s0 = xb + (long)(2 * kp) * HW + n0 + part * 8;
        const float* s1 = s0 + HW;
        unsigned* xo = xpk + (long)b * 64 * HW + (long)kp * HW + n0 + part * 8;
        int nb_ = part * 8;
        #pragma unroll
        for (int q4 = 0; q4 < 2; ++q4) {
            float4 lo = *(const float4*)(s0 + q4 * 4);
            float4 hi = *(const float4*)(s1 + q4 * 4);
            uint4 o;
            o.x = packh2(lo.x, hi.x);
            o.y = packh2(lo.y, hi.y);
            o.z = packh2(lo.z, hi.z);
            o.w = packh2(lo.w, hi.w);
            Bs[nb_ + q4 * 4 + 0][kp] = o.x;
            Bs[nb_ + q4 * 4 + 1][kp] = o.y;
            Bs[nb_ + q4 * 4 + 2][kp] = o.z;
            Bs[nb_ + q4 * 4 + 3][kp] = o.w;
            *(uint4*)(xo + q4 * 4) = o;
        }
    }
    __syncthreads();
    int w = tid >> 6, l = tid & 63;      // 8 waves
    int lr = l & 15, lg = l >> 4;
    f32x4 acc[3][4] = {};
    #pragma unroll
    for (int kk = 0; kk < 4; ++kk) {
        f16x8 af[3];
        #pragma unroll
        for (int mt = 0; mt < 3; ++mt) {
            int m = (w * 3 + mt) * 16 + lr;
            af[mt] = *(const f16x8*)(wpk + (long)m * 64 + kk * 16 + lg * 4);
        }
        #pragma unroll
        for (int ns = 0; ns < 4; ++ns) {
            f16x8 bf = *(const f16x8*)(&Bs[ns * 16 + lr][kk * 16 + lg * 4]);
            #pragma unroll
            for (int mt = 0; mt < 3; ++mt)
                acc[mt][ns] = __builtin_amdgcn_mfma_f32_16x16x32_f16(
                    af[mt], bf, acc[mt][ns], 0, 0, 0);
        }
    }
    #pragma unroll
    for (int mt = 0; mt < 3; ++mt) {
        int m0 = (w * 3 + mt) * 16 + lg * 4;
        float b0v = posb[m0], b1v = posb[m0 + 1], b2v = posb[m0 + 2], b3v = posb[m0 + 3];
        int p0 = m0 >> 1;
        #pragma unroll
        for (int ns = 0; ns < 4; ++ns) {
            int col = n0 + ns * 16 + lr;
            tb[(long)p0 * HW + col]       = packh2(acc[mt][ns][0] + b0v, acc[mt][ns][1] + b1v);
            tb[(long)(p0 + 1) * HW + col] = packh2(acc[mt][ns][2] + b2v, acc[mt][ns][3] + b3v);
        }
    }
}

// ---------------- merged conv3+conv5 via f16 dot2; src pair-packed u32 planes.
// 16 output rows per block, 8 px per thread, 2 groups per block.
__global__ __launch_bounds__(256) void dualconv(
    const unsigned* __restrict__ src, int srcP,   // [NB][srcP][HW] u32
    const unsigned* __restrict__ w3pk, const float* __restrict__ b3,
    const unsigned* __restrict__ w5pk, const float* __restrict__ b5,
    int s3, unsigned short* __restrict__ r3a, long st3a,
    unsigned short* __restrict__ r3b, long st3b,
    int s5, unsigned short* __restrict__ r5a, long st5a,
    unsigned short* __restrict__ r5b, long st5b)
{
    int gp = blockIdx.y, b = blockIdx.z, y0 = blockIdx.x * 16;
    __shared__ __align__(16) unsigned tile[2][20][132];
    int tid = threadIdx.x;
    const unsigned* sU = src + ((long)b * srcP + 2 * gp) * HW;
    const int TOT = 2 * 20 * 132;       // 5280
    for (int idx = tid; idx < TOT; idx += 256) {
        int gi = idx / (20 * 132);
        int rem = idx - gi * (20 * 132);
        int r = rem / 132, ci = rem - r * 132;
        int row = y0 + r - 2, col = ci - 2;
        unsigned u = 0;
        if ((unsigned)row < (unsigned)HH && (unsigned)col < (unsigned)WW)
            u = sU[(long)gi * HW + row * WW + col];
        tile[gi][r][ci] = u;
    }
    __syncthreads();
    int xq = tid & 15, yy = tid >> 4;   // 16 col-groups x 16 rows
    int x0 = xq * 8;
    float a3[2][8], a5[2][8];
    #pragma unroll
    for (int gi = 0; gi < 2; ++gi) {
        int g = 2 * gp + gi;
        #pragma unroll
        for (int j = 0; j < 8; ++j) { a3[gi][j] = b3[g]; a5[gi][j] = b5[g]; }
        unsigned w5v[25], w3v[9];
        #pragma unroll
        for (int i = 0; i < 25; ++i) w5v[i] = w5pk[g * 25 + i];
        #pragma unroll
        for (int i = 0; i < 9; ++i) w3v[i] = w3pk[g * 9 + i];
        #pragma unroll
        for (int r = 0; r < 5; ++r) {
            const unsigned* p = &tile[gi][yy + r][x0];
            unsigned win[12];
            *(f32x4*)win = *(const f32x4*)p;
            *(f32x4*)(win + 4) = *(const f32x4*)(p + 4);
            *(f32x4*)(win + 8) = *(const f32x4*)(p + 8);
            #pragma unroll
            for (int dx = 0; dx < 5; ++dx)
                #pragma unroll
                for (int j = 0; j < 8; ++j)
                    a5[gi][j] = dot2acc(win[j + dx], w5v[r * 5 + dx], a5[gi][j]);
            if (r >= 1 && r <= 3) {
                #pragma unroll
                for (int dx = 0; dx < 3; ++dx)
                    #pragma unroll
                    for (int j = 0; j < 8; ++j)
                        a3[gi][j] = dot2acc(win[j + dx + 1], w3v[(r - 1) * 3 + dx], a3[gi][j]);
            }
        }
    }
    long prow = (long)(y0 + yy) * WW + x0;
    #pragma unroll
    for (int gi = 0; gi < 2; ++gi) {
        int g = 2 * gp + gi;
        uint4 v3, v5;
        v3.x = packbf(a3[gi][0], a3[gi][1]);
        v3.y = packbf(a3[gi][2], a3[gi][3]);
        v3.z = packbf(a3[gi][4], a3[gi][5]);
        v3.w = packbf(a3[gi][6], a3[gi][7]);
        v5.x = packbf(a5[gi][0], a5[gi][1]);
        v5.y = packbf(a5[gi][2], a5[gi][3]);
        v5.z = packbf(a5[gi][4], a5[gi][5]);
        v5.w = packbf(a5[gi][6], a5[gi][7]);
        unsigned short* d3 = (g < s3) ? r3a + (long)b * st3a + (long)g * HW
                                      : r3b + (long)b * st3b + (long)(g - s3) * HW;
        unsigned short* d5 = (g < s5) ? r5a + (long)b * st5a + (long)g * HW
                                      : r5b + (long)b * st5b + (long)(g - s5) * HW;
        *(uint4*)(d3 + prow) = v3;
        *(uint4*)(d5 + prow) = v5;
    }
}

// ---------------- Gram + norms, 3 MFMAs per iter (S, q.q^T diag, k.k^T diag)
__global__ __launch_bounds__(64) void gram_mfma(
    const unsigned short* __restrict__ q,  // [NB][128][HW] bf16
    const unsigned short* __restrict__ k,
    float* __restrict__ gbuf)              // [NB*8][288]
{
    int bh = blockIdx.x, chunk = blockIdx.y;
    int b = bh >> 3, h = bh & 7;
    int l = threadIdx.x;
    int r = l & 15, koff = (l >> 4) * 8;
    const unsigned short* qrow = q + ((long)b * 128 + h * 16 + r) * HW;
    const unsigned short* krow = k + ((long)b * 128 + h * 16 + r) * HW;
    f32x4 accS = {0.f, 0.f, 0.f, 0.f};
    f32x4 accQ = {0.f, 0.f, 0.f, 0.f};
    f32x4 accK = {0.f, 0.f, 0.f, 0.f};
    int n0 = chunk * 256;
    for (int n = n0; n < n0 + 256; n += 32) {
        bf16x8 af = *(const bf16x8*)(qrow + n + koff);
        bf16x8 bf = *(const bf16x8*)(krow + n + koff);
        accS = __builtin_amdgcn_mfma_f32_16x16x32_bf16(af, bf, accS, 0, 0, 0);
        accQ = __builtin_amdgcn_mfma_f32_16x16x32_bf16(af, af, accQ, 0, 0, 0);
        accK = __builtin_amdgcn_mfma_f32_16x16x32_bf16(bf, bf, accK, 0, 0, 0);
    }
    float* gb = gbuf + bh * 288;
    #pragma unroll
    for (int reg = 0; reg < 4; ++reg) {
        int row = (l >> 4) * 4 + reg;
        atomicAdd(&gb[row * 16 + r], accS[reg]);
        if (row == r) {
            atomicAdd(&gb[256 + r], accQ[reg]);
            atomicAdd(&gb[272 + r], accK[reg]);
        }
    }
}

// ---------------- softmax + fold into packed bf16 proj weights
__global__ __launch_bounds__(256) void attn_fold(
    const float* __restrict__ gbuf, const float* __restrict__ temp,
    const float* __restrict__ projw,     // [128][256]
    unsigned* __restrict__ wallpk)       // [NB][128][128] u32 bf16-pairs
{
    int bh = blockIdx.x;
    int b = bh >> 3, h = bh & 7;
    const float* gb = gbuf + bh * 288;
    __shared__ float logit[16][16];
    __shared__ float A[16][16];
    int tid = threadIdx.x;
    int d = tid >> 4, e = tid & 15;
    {
        float nq = fmaxf(sqrtf(gb[256 + d]), 1e-12f);
        float nk = fmaxf(sqrtf(gb[272 + e]), 1e-12f);
        logit[d][e] = gb[d * 16 + e] / (nq * nk) * temp[h];
    }
    __syncthreads();
    float m = -1e30f;
    #pragma unroll
    for (int j = 0; j < 16; ++j) m = fmaxf(m, logit[d][j]);
    float ex = expf(logit[d][e] - m);
    A[d][e] = ex;
    __syncthreads();
    float sum = 0.f;
    #pragma unroll
    for (int j = 0; j < 16; ++j) sum += A[d][j];
    __syncthreads();
    A[d][e] = ex / sum;
    __syncthreads();
    int ep = tid & 7, co0 = tid >> 3;
    for (int co = co0; co < 128; co += 32) {
        float lo = 0.f, hi = 0.f;
        #pragma unroll
        for (int dd = 0; dd < 16; ++dd) {
            float pw = projw[co * 256 + h * 16 + dd];
            lo += pw * A[dd][2 * ep];
            hi += pw * A[dd][2 * ep + 1];
        }
        wallpk[((long)b * 128 + co) * 128 + h * 8 + ep] = packbf(lo, hi);
    }
    if (h == 0) {
        for (int idx = tid; idx < 128 * 64; idx += 256) {
            int co = idx >> 6, cp = idx & 63;
            wallpk[((long)b * 128 + co) * 128 + 64 + cp] =
                packbf(projw[co * 256 + 128 + 2 * cp], projw[co * 256 + 129 + 2 * cp]);
        }
    }
}

// ---------------- K6: out f32 = wallpk @ vy  (M=128, K=256, N-tile 64)
__global__ __launch_bounds__(256) void gemm_out(
    const unsigned* __restrict__ wpk,       // [NB][128][128] u32 (L2)
    const unsigned short* __restrict__ vy,  // [NB][256][HW] bf16
    float* __restrict__ out)                // [NB][128][HW]
{
    int b = blockIdx.z;
    int n0 = blockIdx.x * 64;
    const unsigned* wb = wpk + (long)b * 128 * 128;
    const unsigned short* vyb = vy + (long)b * 256 * HW;
    float* ob = out + (long)b * 128 * HW;
    __shared__ unsigned Bs[64][129];
    int tid = threadIdx.x;
    {   // stage 64 n x 128 kp
        int kp = tid >> 1, nh = (tid & 1) * 32;
        const unsigned short* s0 = vyb + (long)(2 * kp) * HW + n0 + nh;
        const unsigned short* s1 = s0 + HW;
        #pragma unroll
        for (int q4 = 0; q4 < 4; ++q4) {
            us4 lo0 = *(const us4*)(s0 + q4 * 8);
            us4 lo1 = *(const us4*)(s0 + q4 * 8 + 4);
            us4 hi0 = *(const us4*)(s1 + q4 * 8);
            us4 hi1 = *(const us4*)(s1 + q4 * 8 + 4);
            #pragma unroll
            for (int j = 0; j < 4; ++j) {
                Bs[nh + q4 * 8 + j][kp]     = (unsigned)lo0[j] | ((unsigned)hi0[j] << 16);
                Bs[nh + q4 * 8 + 4 + j][kp] = (unsigned)lo1[j] | ((unsigned)hi1[j] << 16);
            }
        }
    }
    __syncthreads();
    int w = tid >> 6, l = tid & 63;
    int lr = l & 15, lg = l >> 4;
    f32x4 acc[2][4] = {};
    #pragma unroll
    for (int kk = 0; kk < 8; ++kk) {
        bf16x8 af[2];
        #pragma unroll
        for (int i = 0; i < 2; ++i) {
            int m = (w * 2 + i) * 16 + lr;
            af[i] = *(const bf16x8*)(wb + (long)m * 128 + kk * 16 + lg * 4);
        }
        #pragma unroll
        for (int ns = 0; ns < 4; ++ns) {
            bf16x8 bf = *(const bf16x8*)(&Bs[ns * 16 + lr][kk * 16 + lg * 4]);
            #pragma unroll
            for (int i = 0; i < 2; ++i)
                acc[i][ns] = __builtin_amdgcn_mfma_f32_16x16x32_bf16(
                    af[i], bf, acc[i][ns], 0, 0, 0);
        }
    }
    #pragma unroll
    for (int i = 0; i < 2; ++i)
        #pragma unroll
        for (int ns = 0; ns < 4; ++ns)
            #pragma unroll
            for (int reg = 0; reg < 4; ++reg) {
                int m = (w * 2 + i) * 16 + lg * 4 + reg;
                ob[(long)m * HW + n0 + ns * 16 + lr] = acc[i][ns][reg];
            }
}

extern "C" void kernel_launch(void* const* d_in, const int* in_sizes, int n_in,
                              void* d_out, int out_size, void* d_ws, size_t ws_size,
                              hipStream_t stream) {
    const float* x      = (const float*)d_in[0];
    const float* pos_w  = (const float*)d_in[1];
    const float* pos_b  = (const float*)d_in[2];
    const float* qd3_w  = (const float*)d_in[3];
    const float* qd3_b  = (const float*)d_in[4];
    const float* qd5_w  = (const float*)d_in[5];
    const float* qd5_b  = (const float*)d_in[6];
    const float* temp   = (const float*)d_in[7];
    const float* d3_w   = (const float*)d_in[8];
    const float* d3_b   = (const float*)d_in[9];
    const float* d5_w   = (const float*)d_in[10];
    const float* d5_b   = (const float*)d_in[11];
    const float* proj_w = (const float*)d_in[12];
    float* out = (float*)d_out;

    // per-batch: tpk 12.58MB + (xpk|qb) 4.19 + kb 4.19 + vy 8.39 + wallpk 64K
    size_t perb = (size_t)HW * 1792 + 65536;
    size_t fixedb = 64UL * 288 * 4 + 384UL * 64 * 4 + 8704UL * 4;
    int NB = 8;
    while (NB > 1 && (size_t)NB * perb + fixedb > ws_size) NB >>= 1;

    char* base = (char*)d_ws;
    unsigned* tpk      = (unsigned*)base;       base += (size_t)NB * 192 * HW * 4;
    unsigned* xpk      = (unsigned*)base;                  // region A (aliased)
    unsigned short* qb = (unsigned short*)base; base += (size_t)NB * 128 * HW * 2;
    unsigned short* kb = (unsigned short*)base; base += (size_t)NB * 128 * HW * 2;
    unsigned short* vy = (unsigned short*)base; base += (size_t)NB * 256 * HW * 2;
    unsigned* wallpk   = (unsigned*)base;       base += (size_t)NB * 128 * 128 * 4;
    float* gram        = (float*)base;          base += 64UL * 288 * 4;
    unsigned* poswpk   = (unsigned*)base;       base += 384UL * 64 * 4;
    unsigned* cwpk     = (unsigned*)base;
    unsigned* qd3pk = cwpk;
    unsigned* qd5pk = cwpk + 192 * 9;
    unsigned* d3pk  = cwpk + 192 * 9 + 192 * 25;
    unsigned* d5pk  = cwpk + 192 * 9 + 192 * 25 + 64 * 9;

    packw<<<(384 * 64 + 255) / 256, 256, 0, stream>>>(pos_w, poswpk);
    packcw<<<(8704 + 255) / 256, 256, 0, stream>>>(qd3_w, qd5_w, d3_w, d5_w, cwpk);

    for (int b0 = 0; b0 < 8; b0 += NB) {
        const float* xb = x + (long)b0 * 128 * HW;
        float* outb = out + (long)b0 * 128 * HW;

        // t (pair-packed) = pos_w @ x + b ; also emits xpk (into qb region)
        gemm_t<<<dim3(HW / 64, 1, NB), 512, 0, stream>>>(poswpk, xb, pos_b, tpk, xpk);

        // convs on x (xpk): conv3 -> vy rows 128..191 ; conv5 -> rows 192..255
        // (must run BEFORE dualconv(t) overwrites the xpk/qb region)
        dualconv<<<dim3(8, 32, NB), 256, 0, stream>>>(
            xpk, 64, d3pk, d3_b, d5pk, d5_b,
            64, vy + 128L * HW, 256L * HW, vy + 128L * HW, 256L * HW,
            64, vy + 192L * HW, 256L * HW, vy + 192L * HW, 256L * HW);

        // convs on t: conv3: g<128 -> q(qb) ; g>=128 -> k rows 0..63
        //             conv5: g<64 -> k rows 64..127 ; g>=64 -> vy rows 0..127
        dualconv<<<dim3(8, 96, NB), 256, 0, stream>>>(
            tpk, 192, qd3pk, qd3_b, qd5pk, qd5_b,
            128, qb, 128L * HW, kb, 128L * HW,
            64, kb + 64L * HW, 128L * HW, vy, 256L * HW);

        zerok<<<(64 * 288 + 255) / 256, 256, 0, stream>>>(gram, 64 * 288);
        gram_mfma<<<dim3(NB * 8, 64), 64, 0, stream>>>(qb, kb, gram);
        attn_fold<<<NB * 8, 256, 0, stream>>>(gram, temp, proj_w, wallpk);

        gemm_out<<<dim3(HW / 64, 1, NB), 256, 0, stream>>>(wallpk, vy, outb);
    }
}

// Round 18
// 218.776 us; speedup vs baseline: 1.0965x; 1.0047x over previous
//
#include <hip/hip_runtime.h>
#include <hip/hip_bf16.h>

// ---------------------------------------------------------------------------
// B=8, C=128, H=W=128, hw=16384, heads=8.
//  packw/packcw (once): weights -> f16-pair packed
//  K1 gemm_t: tpk = f16-pair-packed(pos_w @ x + pos_b) (MFMA f16)
//             512 threads, 8 waves x 3 m-tiles (r17 win); emits xpk too.
//  K2 dualconv(xpk): conv3+conv5 -> vy rows 128..255   (v_dot2, 16-row tile)
//  K3 dualconv(tpk): conv3+conv5 -> q,k,v bf16
//  K4 gram: S, |q|^2, |k|^2 per (b,h) via 3 MFMAs/iter (MFMA bf16)
//  K5 attn_fold: softmax fold -> wallpk (bf16 pairs)
//  K6 gemm_out: out f32 = wallpk @ vy; 512 threads, 8 waves x 1 m-tile (r18)
// r18: (a) dot2 accumulator TIED ("+v", %0 as dst+src2) — removes any
// uncoalesced v_mov per dot2; (b) gemm_out gets the r17 wave-split treatment
// (acc[1][4], 2x waves, single stage).
// ---------------------------------------------------------------------------

#define HW 16384
#define HH 128
#define WW 128

typedef __attribute__((ext_vector_type(8))) short bf16x8;
typedef __attribute__((ext_vector_type(8))) _Float16 f16x8;
typedef __attribute__((ext_vector_type(4))) float f32x4;
typedef __attribute__((ext_vector_type(4))) unsigned short us4;
typedef __fp16 fp16x2 __attribute__((ext_vector_type(2)));

__device__ inline unsigned short f2bf(float f) {
    unsigned u = __float_as_uint(f);
    return (unsigned short)((u + 0x7FFFu + ((u >> 16) & 1u)) >> 16);
}
__device__ inline unsigned packbf(float lo, float hi) {
    return (unsigned)f2bf(lo) | ((unsigned)f2bf(hi) << 16);
}
__device__ inline unsigned short f2h(float f) {
    _Float16 h = (_Float16)f;
    return __builtin_bit_cast(unsigned short, h);
}
__device__ inline unsigned packh(float lo, float hi) {
    return (unsigned)f2h(lo) | ((unsigned)f2h(hi) << 16);
}
// 1-instr packed f32->f16 (RTZ): v_cvt_pkrtz_f16_f32
__device__ inline unsigned packh2(float lo, float hi) {
    fp16x2 h = __builtin_amdgcn_cvt_pkrtz(lo, hi);
    return __builtin_bit_cast(unsigned, h);
}

// c += a.lo*w.lo + a.hi*w.hi ; TIED accumulator (no mov possible).
__device__ inline float dot2acc(unsigned a, unsigned w, float c) {
    asm("v_dot2_f32_f16 %0, %1, %2, %0" : "+v"(c) : "v"(a), "s"(w));
    return c;
}

__global__ void zerok(float* p, int n) {
    int i = blockIdx.x * 256 + threadIdx.x;
    if (i < n) p[i] = 0.f;
}

// pack pos_w [384][128] f32 -> poswpk [384][64] u32 (f16 pairs along k)
__global__ __launch_bounds__(256) void packw(const float* __restrict__ w,
                                             unsigned* __restrict__ wpk) {
    int id = blockIdx.x * 256 + threadIdx.x;
    if (id >= 384 * 64) return;
    int m = id >> 6, kp = id & 63;
    wpk[id] = packh(w[m * 128 + 2 * kp], w[m * 128 + 2 * kp + 1]);
}

// pack conv weights: channel-pair f16 per tap.
__global__ __launch_bounds__(256) void packcw(
    const float* __restrict__ qd3, const float* __restrict__ qd5,
    const float* __restrict__ d3, const float* __restrict__ d5,
    unsigned* __restrict__ o) {
    int id = blockIdx.x * 256 + threadIdx.x;
    if (id < 192 * 9) {
        int g = id / 9, tp = id % 9;
        o[id] = packh(qd3[(g * 2) * 9 + tp], qd3[(g * 2 + 1) * 9 + tp]);
    } else if (id < 192 * 9 + 192 * 25) {
        int r = id - 192 * 9; int g = r / 25, tp = r % 25;
        o[id] = packh(qd5[(g * 2) * 25 + tp], qd5[(g * 2 + 1) * 25 + tp]);
    } else if (id < 192 * 9 + 192 * 25 + 64 * 9) {
        int r = id - 192 * 9 - 192 * 25; int g = r / 9, tp = r % 9;
        o[id] = packh(d3[(g * 2) * 9 + tp], d3[(g * 2 + 1) * 9 + tp]);
    } else if (id < 192 * 9 + 192 * 25 + 64 * 9 + 64 * 25) {
        int r = id - 192 * 9 - 192 * 25 - 64 * 9; int g = r / 25, tp = r % 25;
        o[id] = packh(d5[(g * 2) * 25 + tp], d5[(g * 2 + 1) * 25 + tp]);
    }
}

// ---------------- K1: tpk = f16-pair-packed(pos_w @ x + b); 512 threads,
// 8 waves x 3 m-tiles; single stage; scatter epilogue; emits xpk.
__global__ __launch_bounds__(512) void gemm_t(
    const unsigned* __restrict__ wpk,   // [384][64] u32 f16 k-pairs (L2)
    const float* __restrict__ x,        // [NB][128][HW] f32
    const float* __restrict__ posb,     // [384]
    unsigned* __restrict__ tpk,         // [NB][192][HW] u32 f16 ch-pairs
    unsigned* __restrict__ xpk)         // [NB][64][HW] u32 f16 ch-pairs
{
    int b = blockIdx.z;
    int n0 = blockIdx.x * 64;
    const float* xb = x + (long)b * 128 * HW;
    unsigned* tb = tpk + (long)b * 192 * HW;
    __shared__ unsigned Bs[64][65];     // [n][kp], 16.6KB
    int tid = threadIdx.x;
    {   // stage 64 n x 64 kp: 512 threads, kp=tid>>3, 8 cols each
        int kp = tid >> 3, part = tid & 7;
        const float* s0 = xb + (long)(2 * kp) * HW + n0 + part * 8;
        const float* s1 = s0 + HW;
        unsigned* xo = xpk + (long)b * 64 * HW + (long)kp * HW + n0 + part * 8;
        int nb_ = part * 8;
        #pragma unroll
        for (int q4 = 0; q4 < 2; ++q4) {
            float4 lo = *(const float4*)(s0 + q4 * 4);
            float4 hi = *(const float4*)(s1 + q4 * 4);
            uint4 o;
            o.x = packh2(lo.x, hi.x);
            o.y = packh2(lo.y, hi.y);
            o.z = packh2(lo.z, hi.z);
            o.w = packh2(lo.w, hi.w);
            Bs[nb_ + q4 * 4 + 0][kp] = o.x;
            Bs[nb_ + q4 * 4 + 1][kp] = o.y;
            Bs[nb_ + q4 * 4 + 2][kp] = o.z;
            Bs[nb_ + q4 * 4 + 3][kp] = o.w;
            *(uint4*)(xo + q4 * 4) = o;
        }
    }
    __syncthreads();
    int w = tid >> 6, l = tid & 63;      // 8 waves
    int lr = l & 15, lg = l >> 4;
    f32x4 acc[3][4] = {};
    #pragma unroll
    for (int kk = 0; kk < 4; ++kk) {
        f16x8 af[3];
        #pragma unroll
        for (int mt = 0; mt < 3; ++mt) {
            int m = (w * 3 + mt) * 16 + lr;
            af[mt] = *(const f16x8*)(wpk + (long)m * 64 + kk * 16 + lg * 4);
        }
        #pragma unroll
        for (int ns = 0; ns < 4; ++ns) {
            f16x8 bf = *(const f16x8*)(&Bs[ns * 16 + lr][kk * 16 + lg * 4]);
            #pragma unroll
            for (int mt = 0; mt < 3; ++mt)
                acc[mt][ns] = __builtin_amdgcn_mfma_f32_16x16x32_f16(
                    af[mt], bf, acc[mt][ns], 0, 0, 0);
        }
    }
    #pragma unroll
    for (int mt = 0; mt < 3; ++mt) {
        int m0 = (w * 3 + mt) * 16 + lg * 4;
        float b0v = posb[m0], b1v = posb[m0 + 1], b2v = posb[m0 + 2], b3v = posb[m0 + 3];
        int p0 = m0 >> 1;
        #pragma unroll
        for (int ns = 0; ns < 4; ++ns) {
            int col = n0 + ns * 16 + lr;
            tb[(long)p0 * HW + col]       = packh2(acc[mt][ns][0] + b0v, acc[mt][ns][1] + b1v);
            tb[(long)(p0 + 1) * HW + col] = packh2(acc[mt][ns][2] + b2v, acc[mt][ns][3] + b3v);
        }
    }
}

// ---------------- merged conv3+conv5 via f16 dot2; src pair-packed u32 planes.
// 16 output rows per block, 8 px per thread, 2 groups per block.
__global__ __launch_bounds__(256) void dualconv(
    const unsigned* __restrict__ src, int srcP,   // [NB][srcP][HW] u32
    const unsigned* __restrict__ w3pk, const float* __restrict__ b3,
    const unsigned* __restrict__ w5pk, const float* __restrict__ b5,
    int s3, unsigned short* __restrict__ r3a, long st3a,
    unsigned short* __restrict__ r3b, long st3b,
    int s5, unsigned short* __restrict__ r5a, long st5a,
    unsigned short* __restrict__ r5b, long st5b)
{
    int gp = blockIdx.y, b = blockIdx.z, y0 = blockIdx.x * 16;
    __shared__ __align__(16) unsigned tile[2][20][132];
    int tid = threadIdx.x;
    const unsigned* sU = src + ((long)b * srcP + 2 * gp) * HW;
    const int TOT = 2 * 20 * 132;       // 5280
    for (int idx = tid; idx < TOT; idx += 256) {
        int gi = idx / (20 * 132);
        int rem = idx - gi * (20 * 132);
        int r = rem / 132, ci = rem - r * 132;
        int row = y0 + r - 2, col = ci - 2;
        unsigned u = 0;
        if ((unsigned)row < (unsigned)HH && (unsigned)col < (unsigned)WW)
            u = sU[(long)gi * HW + row * WW + col];
        tile[gi][r][ci] = u;
    }
    __syncthreads();
    int xq = tid & 15, yy = tid >> 4;   // 16 col-groups x 16 rows
    int x0 = xq * 8;
    float a3[2][8], a5[2][8];
    #pragma unroll
    for (int gi = 0; gi < 2; ++gi) {
        int g = 2 * gp + gi;
        #pragma unroll
        for (int j = 0; j < 8; ++j) { a3[gi][j] = b3[g]; a5[gi][j] = b5[g]; }
        unsigned w5v[25], w3v[9];
        #pragma unroll
        for (int i = 0; i < 25; ++i) w5v[i] = w5pk[g * 25 + i];
        #pragma unroll
        for (int i = 0; i < 9; ++i) w3v[i] = w3pk[g * 9 + i];
        #pragma unroll
        for (int r = 0; r < 5; ++r) {
            const unsigned* p = &tile[gi][yy + r][x0];
            unsigned win[12];
            *(f32x4*)win = *(const f32x4*)p;
            *(f32x4*)(win + 4) = *(const f32x4*)(p + 4);
            *(f32x4*)(win + 8) = *(const f32x4*)(p + 8);
            #pragma unroll
            for (int dx = 0; dx < 5; ++dx)
                #pragma unroll
                for (int j = 0; j < 8; ++j)
                    a5[gi][j] = dot2acc(win[j + dx], w5v[r * 5 + dx], a5[gi][j]);
            if (r >= 1 && r <= 3) {
                #pragma unroll
                for (int dx = 0; dx < 3; ++dx)
                    #pragma unroll
                    for (int j = 0; j < 8; ++j)
                        a3[gi][j] = dot2acc(win[j + dx + 1], w3v[(r - 1) * 3 + dx], a3[gi][j]);
            }
        }
    }
    long prow = (long)(y0 + yy) * WW + x0;
    #pragma unroll
    for (int gi = 0; gi < 2; ++gi) {
        int g = 2 * gp + gi;
        uint4 v3, v5;
        v3.x = packbf(a3[gi][0], a3[gi][1]);
        v3.y = packbf(a3[gi][2], a3[gi][3]);
        v3.z = packbf(a3[gi][4], a3[gi][5]);
        v3.w = packbf(a3[gi][6], a3[gi][7]);
        v5.x = packbf(a5[gi][0], a5[gi][1]);
        v5.y = packbf(a5[gi][2], a5[gi][3]);
        v5.z = packbf(a5[gi][4], a5[gi][5]);
        v5.w = packbf(a5[gi][6], a5[gi][7]);
        unsigned short* d3 = (g < s3) ? r3a + (long)b * st3a + (long)g * HW
                                      : r3b + (long)b * st3b + (long)(g - s3) * HW;
        unsigned short* d5 = (g < s5) ? r5a + (long)b * st5a + (long)g * HW
                                      : r5b + (long)b * st5b + (long)(g - s5) * HW;
        *(uint4*)(d3 + prow) = v3;
        *(uint4*)(d5 + prow) = v5;
    }
}

// ---------------- Gram + norms, 3 MFMAs per iter (S, q.q^T diag, k.k^T diag)
__global__ __launch_bounds__(64) void gram_mfma(
    const unsigned short* __restrict__ q,  // [NB][128][HW] bf16
    const unsigned short* __restrict__ k,
    float* __restrict__ gbuf)              // [NB*8][288]
{
    int bh = blockIdx.x, chunk = blockIdx.y;
    int b = bh >> 3, h = bh & 7;
    int l = threadIdx.x;
    int r = l & 15, koff = (l >> 4) * 8;
    const unsigned short* qrow = q + ((long)b * 128 + h * 16 + r) * HW;
    const unsigned short* krow = k + ((long)b * 128 + h * 16 + r) * HW;
    f32x4 accS = {0.f, 0.f, 0.f, 0.f};
    f32x4 accQ = {0.f, 0.f, 0.f, 0.f};
    f32x4 accK = {0.f, 0.f, 0.f, 0.f};
    int n0 = chunk * 256;
    for (int n = n0; n < n0 + 256; n += 32) {
        bf16x8 af = *(const bf16x8*)(qrow + n + koff);
        bf16x8 bf = *(const bf16x8*)(krow + n + koff);
        accS = __builtin_amdgcn_mfma_f32_16x16x32_bf16(af, bf, accS, 0, 0, 0);
        accQ = __builtin_amdgcn_mfma_f32_16x16x32_bf16(af, af, accQ, 0, 0, 0);
        accK = __builtin_amdgcn_mfma_f32_16x16x32_bf16(bf, bf, accK, 0, 0, 0);
    }
    float* gb = gbuf + bh * 288;
    #pragma unroll
    for (int reg = 0; reg < 4; ++reg) {
        int row = (l >> 4) * 4 + reg;
        atomicAdd(&gb[row * 16 + r], accS[reg]);
        if (row == r) {
            atomicAdd(&gb[256 + r], accQ[reg]);
            atomicAdd(&gb[272 + r], accK[reg]);
        }
    }
}

// ---------------- softmax + fold into packed bf16 proj weights
__global__ __launch_bounds__(256) void attn_fold(
    const float* __restrict__ gbuf, const float* __restrict__ temp,
    const float* __restrict__ projw,     // [128][256]
    unsigned* __restrict__ wallpk)       // [NB][128][128] u32 bf16-pairs
{
    int bh = blockIdx.x;
    int b = bh >> 3, h = bh & 7;
    const float* gb = gbuf + bh * 288;
    __shared__ float logit[16][16];
    __shared__ float A[16][16];
    int tid = threadIdx.x;
    int d = tid >> 4, e = tid & 15;
    {
        float nq = fmaxf(sqrtf(gb[256 + d]), 1e-12f);
        float nk = fmaxf(sqrtf(gb[272 + e]), 1e-12f);
        logit[d][e] = gb[d * 16 + e] / (nq * nk) * temp[h];
    }
    __syncthreads();
    float m = -1e30f;
    #pragma unroll
    for (int j = 0; j < 16; ++j) m = fmaxf(m, logit[d][j]);
    float ex = expf(logit[d][e] - m);
    A[d][e] = ex;
    __syncthreads();
    float sum = 0.f;
    #pragma unroll
    for (int j = 0; j < 16; ++j) sum += A[d][j];
    __syncthreads();
    A[d][e] = ex / sum;
    __syncthreads();
    int ep = tid & 7, co0 = tid >> 3;
    for (int co = co0; co < 128; co += 32) {
        float lo = 0.f, hi = 0.f;
        #pragma unroll
        for (int dd = 0; dd < 16; ++dd) {
            float pw = projw[co * 256 + h * 16 + dd];
            lo += pw * A[dd][2 * ep];
            hi += pw * A[dd][2 * ep + 1];
        }
        wallpk[((long)b * 128 + co) * 128 + h * 8 + ep] = packbf(lo, hi);
    }
    if (h == 0) {
        for (int idx = tid; idx < 128 * 64; idx += 256) {
            int co = idx >> 6, cp = idx & 63;
            wallpk[((long)b * 128 + co) * 128 + 64 + cp] =
                packbf(projw[co * 256 + 128 + 2 * cp], projw[co * 256 + 129 + 2 * cp]);
        }
    }
}

// ---------------- K6: out f32 = wallpk @ vy  (M=128, K=256, N-tile 64)
// 512 threads, 8 waves x 1 m-tile (r18 wave-split).
__global__ __launch_bounds__(512) void gemm_out(
    const unsigned* __restrict__ wpk,       // [NB][128][128] u32 (L2)
    const unsigned short* __restrict__ vy,  // [NB][256][HW] bf16
    float* __restrict__ out)                // [NB][128][HW]
{
    int b = blockIdx.z;
    int n0 = blockIdx.x * 64;
    const unsigned* wb = wpk + (long)b * 128 * 128;
    const unsigned short* vyb = vy + (long)b * 256 * HW;
    float* ob = out + (long)b * 128 * HW;
    __shared__ unsigned Bs[64][129];
    int tid = threadIdx.x;
    {   // stage 64 n x 128 kp: 512 threads, kp=tid>>2, 16 cols each
        int kp = tid >> 2, nh = (tid & 3) * 16;
        const unsigned short* s0 = vyb + (long)(2 * kp) * HW + n0 + nh;
        const unsigned short* s1 = s0 + HW;
        #pragma unroll
        for (int q4 = 0; q4 < 4; ++q4) {
            us4 lo = *(const us4*)(s0 + q4 * 4);
            us4 hi = *(const us4*)(s1 + q4 * 4);
            #pragma unroll
            for (int j = 0; j < 4; ++j)
                Bs[nh + q4 * 4 + j][kp] = (unsigned)lo[j] | ((unsigned)hi[j] << 16);
        }
    }
    __syncthreads();
    int w = tid >> 6, l = tid & 63;      // 8 waves, 1 m-tile each
    int lr = l & 15, lg = l >> 4;
    f32x4 acc[4] = {};
    #pragma unroll
    for (int kk = 0; kk < 8; ++kk) {
        int m = w * 16 + lr;
        bf16x8 af = *(const bf16x8*)(wb + (long)m * 128 + kk * 16 + lg * 4);
        #pragma unroll
        for (int ns = 0; ns < 4; ++ns) {
            bf16x8 bf = *(const bf16x8*)(&Bs[ns * 16 + lr][kk * 16 + lg * 4]);
            acc[ns] = __builtin_amdgcn_mfma_f32_16x16x32_bf16(af, bf, acc[ns], 0, 0, 0);
        }
    }
    #pragma unroll
    for (int ns = 0; ns < 4; ++ns)
        #pragma unroll
        for (int reg = 0; reg < 4; ++reg) {
            int m = w * 16 + lg * 4 + reg;
            ob[(long)m * HW + n0 + ns * 16 + lr] = acc[ns][reg];
        }
}

extern "C" void kernel_launch(void* const* d_in, const int* in_sizes, int n_in,
                              void* d_out, int out_size, void* d_ws, size_t ws_size,
                              hipStream_t stream) {
    const float* x      = (const float*)d_in[0];
    const float* pos_w  = (const float*)d_in[1];
    const float* pos_b  = (const float*)d_in[2];
    const float* qd3_w  = (const float*)d_in[3];
    const float* qd3_b  = (const float*)d_in[4];
    const float* qd5_w  = (const float*)d_in[5];
    const float* qd5_b  = (const float*)d_in[6];
    const float* temp   = (const float*)d_in[7];
    const float* d3_w   = (const float*)d_in[8];
    const float* d3_b   = (const float*)d_in[9];
    const float* d5_w   = (const float*)d_in[10];
    const float* d5_b   = (const float*)d_in[11];
    const float* proj_w = (const float*)d_in[12];
    float* out = (float*)d_out;

    // per-batch: tpk 12.58MB + (xpk|qb) 4.19 + kb 4.19 + vy 8.39 + wallpk 64K
    size_t perb = (size_t)HW * 1792 + 65536;
    size_t fixedb = 64UL * 288 * 4 + 384UL * 64 * 4 + 8704UL * 4;
    int NB = 8;
    while (NB > 1 && (size_t)NB * perb + fixedb > ws_size) NB >>= 1;

    char* base = (char*)d_ws;
    unsigned* tpk      = (unsigned*)base;       base += (size_t)NB * 192 * HW * 4;
    unsigned* xpk      = (unsigned*)base;                  // region A (aliased)
    unsigned short* qb = (unsigned short*)base; base += (size_t)NB * 128 * HW * 2;
    unsigned short* kb = (unsigned short*)base; base += (size_t)NB * 128 * HW * 2;
    unsigned short* vy = (unsigned short*)base; base += (size_t)NB * 256 * HW * 2;
    unsigned* wallpk   = (unsigned*)base;       base += (size_t)NB * 128 * 128 * 4;
    float* gram        = (float*)base;          base += 64UL * 288 * 4;
    unsigned* poswpk   = (unsigned*)base;       base += 384UL * 64 * 4;
    unsigned* cwpk     = (unsigned*)base;
    unsigned* qd3pk = cwpk;
    unsigned* qd5pk = cwpk + 192 * 9;
    unsigned* d3pk  = cwpk + 192 * 9 + 192 * 25;
    unsigned* d5pk  = cwpk + 192 * 9 + 192 * 25 + 64 * 9;

    packw<<<(384 * 64 + 255) / 256, 256, 0, stream>>>(pos_w, poswpk);
    packcw<<<(8704 + 255) / 256, 256, 0, stream>>>(qd3_w, qd5_w, d3_w, d5_w, cwpk);

    for (int b0 = 0; b0 < 8; b0 += NB) {
        const float* xb = x + (long)b0 * 128 * HW;
        float* outb = out + (long)b0 * 128 * HW;

        // t (pair-packed) = pos_w @ x + b ; also emits xpk (into qb region)
        gemm_t<<<dim3(HW / 64, 1, NB), 512, 0, stream>>>(poswpk, xb, pos_b, tpk, xpk);

        // convs on x (xpk): conv3 -> vy rows 128..191 ; conv5 -> rows 192..255
        // (must run BEFORE dualconv(t) overwrites the xpk/qb region)
        dualconv<<<dim3(8, 32, NB), 256, 0, stream>>>(
            xpk, 64, d3pk, d3_b, d5pk, d5_b,
            64, vy + 128L * HW, 256L * HW, vy + 128L * HW, 256L * HW,
            64, vy + 192L * HW, 256L * HW, vy + 192L * HW, 256L * HW);

        // convs on t: conv3: g<128 -> q(qb) ; g>=128 -> k rows 0..63
        //             conv5: g<64 -> k rows 64..127 ; g>=64 -> vy rows 0..127
        dualconv<<<dim3(8, 96, NB), 256, 0, stream>>>(
            tpk, 192, qd3pk, qd3_b, qd5pk, qd5_b,
            128, qb, 128L * HW, kb, 128L * HW,
            64, kb + 64L * HW, 128L * HW, vy, 256L * HW);

        zerok<<<(64 * 288 + 255) / 256, 256, 0, stream>>>(gram, 64 * 288);
        gram_mfma<<<dim3(NB * 8, 64), 64, 0, stream>>>(qb, kb, gram);
        attn_fold<<<NB * 8, 256, 0, stream>>>(gram, temp, proj_w, wallpk);

        gemm_out<<<dim3(HW / 64, 1, NB), 512, 0, stream>>>(wallpk, vy, outb);
    }
}

// Round 19
// 210.104 us; speedup vs baseline: 1.1418x; 1.0413x over previous
//
#include <hip/hip_runtime.h>
#include <hip/hip_bf16.h>

// ---------------------------------------------------------------------------
// B=8, C=128, H=W=128, hw=16384, heads=8.
//  packw/packcw (once): weights -> f16-pair packed
//  K1 gemm_t: tpk = f16-pair-packed(pos_w @ x + pos_b) (MFMA f16)
//             512 threads, 8 waves x 3 m-tiles (r17 win); emits xpk too.
//  K2 dualconv(xpk): conv3+conv5 -> vy rows 128..255   (v_dot2)
//  K3 dualconv(tpk): conv3+conv5 -> q,k,v bf16
//  K4 gram: S, |q|^2, |k|^2 per (b,h) via 3 MFMAs/iter (MFMA bf16)
//  K5 attn_fold: softmax fold -> wallpk (bf16 pairs)
//  K6 gemm_out: out f32 = wallpk @ vy; 512 thr, 8 waves x 1 m-tile (r18 win)
// r19: dualconv gets the r17 treatment — 512 threads / 8 waves, 32 output
// rows per block (halo 1.125x, LDS 38KB -> 4 blocks x 8 waves = 32 waves/CU).
// Fill-loop shape and dot2 inner loop unchanged (proven since r9).
// ---------------------------------------------------------------------------

#define HW 16384
#define HH 128
#define WW 128

typedef __attribute__((ext_vector_type(8))) short bf16x8;
typedef __attribute__((ext_vector_type(8))) _Float16 f16x8;
typedef __attribute__((ext_vector_type(4))) float f32x4;
typedef __attribute__((ext_vector_type(4))) unsigned short us4;
typedef __fp16 fp16x2 __attribute__((ext_vector_type(2)));

__device__ inline unsigned short f2bf(float f) {
    unsigned u = __float_as_uint(f);
    return (unsigned short)((u + 0x7FFFu + ((u >> 16) & 1u)) >> 16);
}
__device__ inline unsigned packbf(float lo, float hi) {
    return (unsigned)f2bf(lo) | ((unsigned)f2bf(hi) << 16);
}
__device__ inline unsigned short f2h(float f) {
    _Float16 h = (_Float16)f;
    return __builtin_bit_cast(unsigned short, h);
}
__device__ inline unsigned packh(float lo, float hi) {
    return (unsigned)f2h(lo) | ((unsigned)f2h(hi) << 16);
}
// 1-instr packed f32->f16 (RTZ): v_cvt_pkrtz_f16_f32
__device__ inline unsigned packh2(float lo, float hi) {
    fp16x2 h = __builtin_amdgcn_cvt_pkrtz(lo, hi);
    return __builtin_bit_cast(unsigned, h);
}

// c += a.lo*w.lo + a.hi*w.hi ; tied accumulator.
__device__ inline float dot2acc(unsigned a, unsigned w, float c) {
    asm("v_dot2_f32_f16 %0, %1, %2, %0" : "+v"(c) : "v"(a), "s"(w));
    return c;
}

__global__ void zerok(float* p, int n) {
    int i = blockIdx.x * 256 + threadIdx.x;
    if (i < n) p[i] = 0.f;
}

// pack pos_w [384][128] f32 -> poswpk [384][64] u32 (f16 pairs along k)
__global__ __launch_bounds__(256) void packw(const float* __restrict__ w,
                                             unsigned* __restrict__ wpk) {
    int id = blockIdx.x * 256 + threadIdx.x;
    if (id >= 384 * 64) return;
    int m = id >> 6, kp = id & 63;
    wpk[id] = packh(w[m * 128 + 2 * kp], w[m * 128 + 2 * kp + 1]);
}

// pack conv weights: channel-pair f16 per tap.
__global__ __launch_bounds__(256) void packcw(
    const float* __restrict__ qd3, const float* __restrict__ qd5,
    const float* __restrict__ d3, const float* __restrict__ d5,
    unsigned* __restrict__ o) {
    int id = blockIdx.x * 256 + threadIdx.x;
    if (id < 192 * 9) {
        int g = id / 9, tp = id % 9;
        o[id] = packh(qd3[(g * 2) * 9 + tp], qd3[(g * 2 + 1) * 9 + tp]);
    } else if (id < 192 * 9 + 192 * 25) {
        int r = id - 192 * 9; int g = r / 25, tp = r % 25;
        o[id] = packh(qd5[(g * 2) * 25 + tp], qd5[(g * 2 + 1) * 25 + tp]);
    } else if (id < 192 * 9 + 192 * 25 + 64 * 9) {
        int r = id - 192 * 9 - 192 * 25; int g = r / 9, tp = r % 9;
        o[id] = packh(d3[(g * 2) * 9 + tp], d3[(g * 2 + 1) * 9 + tp]);
    } else if (id < 192 * 9 + 192 * 25 + 64 * 9 + 64 * 25) {
        int r = id - 192 * 9 - 192 * 25 - 64 * 9; int g = r / 25, tp = r % 25;
        o[id] = packh(d5[(g * 2) * 25 + tp], d5[(g * 2 + 1) * 25 + tp]);
    }
}

// ---------------- K1: tpk = f16-pair-packed(pos_w @ x + b); 512 threads,
// 8 waves x 3 m-tiles; single stage; scatter epilogue; emits xpk.
__global__ __launch_bounds__(512) void gemm_t(
    const unsigned* __restrict__ wpk,   // [384][64] u32 f16 k-pairs (L2)
    const float* __restrict__ x,        // [NB][128][HW] f32
    const float* __restrict__ posb,     // [384]
    unsigned* __restrict__ tpk,         // [NB][192][HW] u32 f16 ch-pairs
    unsigned* __restrict__ xpk)         // [NB][64][HW] u32 f16 ch-pairs
{
    int b = blockIdx.z;
    int n0 = blockIdx.x * 64;
    const float* xb = x + (long)b * 128 * HW;
    unsigned* tb = tpk + (long)b * 192 * HW;
    __shared__ unsigned Bs[64][65];     // [n][kp], 16.6KB
    int tid = threadIdx.x;
    {   // stage 64 n x 64 kp: 512 threads, kp=tid>>3, 8 cols each
        int kp = tid >> 3, part = tid & 7;
        const float* s0 = xb + (long)(2 * kp) * HW + n0 + part * 8;
        const float* s1 = s0 + HW;
        unsigned* xo = xpk + (long)b * 64 * HW + (long)kp * HW + n0 + part * 8;
        int nb_ = part * 8;
        #pragma unroll
        for (int q4 = 0; q4 < 2; ++q4) {
            float4 lo = *(const float4*)(s0 + q4 * 4);
            float4 hi = *(const float4*)(s1 + q4 * 4);
            uint4 o;
            o.x = packh2(lo.x, hi.x);
            o.y = packh2(lo.y, hi.y);
            o.z = packh2(lo.z, hi.z);
            o.w = packh2(lo.w, hi.w);
            Bs[nb_ + q4 * 4 + 0][kp] = o.x;
            Bs[nb_ + q4 * 4 + 1][kp] = o.y;
            Bs[nb_ + q4 * 4 + 2][kp] = o.z;
            Bs[nb_ + q4 * 4 + 3][kp] = o.w;
            *(uint4*)(xo + q4 * 4) = o;
        }
    }
    __syncthreads();
    int w = tid >> 6, l = tid & 63;      // 8 waves
    int lr = l & 15, lg = l >> 4;
    f32x4 acc[3][4] = {};
    #pragma unroll
    for (int kk = 0; kk < 4; ++kk) {
        f16x8 af[3];
        #pragma unroll
        for (int mt = 0; mt < 3; ++mt) {
            int m = (w * 3 + mt) * 16 + lr;
            af[mt] = *(const f16x8*)(wpk + (long)m * 64 + kk * 16 + lg * 4);
        }
        #pragma unroll
        for (int ns = 0; ns < 4; ++ns) {
            f16x8 bf = *(const f16x8*)(&Bs[ns * 16 + lr][kk * 16 + lg * 4]);
            #pragma unroll
            for (int mt = 0; mt < 3; ++mt)
                acc[mt][ns] = __builtin_amdgcn_mfma_f32_16x16x32_f16(
                    af[mt], bf, acc[mt][ns], 0, 0, 0);
        }
    }
    #pragma unroll
    for (int mt = 0; mt < 3; ++mt) {
        int m0 = (w * 3 + mt) * 16 + lg * 4;
        float b0v = posb[m0], b1v = posb[m0 + 1], b2v = posb[m0 + 2], b3v = posb[m0 + 3];
        int p0 = m0 >> 1;
        #pragma unroll
        for (int ns = 0; ns < 4; ++ns) {
            int col = n0 + ns * 16 + lr;
            tb[(long)p0 * HW + col]       = packh2(acc[mt][ns][0] + b0v, acc[mt][ns][1] + b1v);
            tb[(long)(p0 + 1) * HW + col] = packh2(acc[mt][ns][2] + b2v, acc[mt][ns][3] + b3v);
        }
    }
}

// ---------------- merged conv3+conv5 via f16 dot2; src pair-packed u32 planes.
// 512 threads / 8 waves; 32 output rows per block; 8 px/thread; 2 groups.
__global__ __launch_bounds__(512) void dualconv(
    const unsigned* __restrict__ src, int srcP,   // [NB][srcP][HW] u32
    const unsigned* __restrict__ w3pk, const float* __restrict__ b3,
    const unsigned* __restrict__ w5pk, const float* __restrict__ b5,
    int s3, unsigned short* __restrict__ r3a, long st3a,
    unsigned short* __restrict__ r3b, long st3b,
    int s5, unsigned short* __restrict__ r5a, long st5a,
    unsigned short* __restrict__ r5b, long st5b)
{
    int gp = blockIdx.y, b = blockIdx.z, y0 = blockIdx.x * 32;
    __shared__ __align__(16) unsigned tile[2][36][132];   // 38KB
    int tid = threadIdx.x;
    const unsigned* sU = src + ((long)b * srcP + 2 * gp) * HW;
    const int TOT = 2 * 36 * 132;       // 9504
    for (int idx = tid; idx < TOT; idx += 512) {
        int gi = idx / (36 * 132);
        int rem = idx - gi * (36 * 132);
        int r = rem / 132, ci = rem - r * 132;
        int row = y0 + r - 2, col = ci - 2;
        unsigned u = 0;
        if ((unsigned)row < (unsigned)HH && (unsigned)col < (unsigned)WW)
            u = sU[(long)gi * HW + row * WW + col];
        tile[gi][r][ci] = u;
    }
    __syncthreads();
    int xq = tid & 15, yy = tid >> 4;   // 16 col-groups x 32 rows
    int x0 = xq * 8;
    float a3[2][8], a5[2][8];
    #pragma unroll
    for (int gi = 0; gi < 2; ++gi) {
        int g = 2 * gp + gi;
        #pragma unroll
        for (int j = 0; j < 8; ++j) { a3[gi][j] = b3[g]; a5[gi][j] = b5[g]; }
        unsigned w5v[25], w3v[9];
        #pragma unroll
        for (int i = 0; i < 25; ++i) w5v[i] = w5pk[g * 25 + i];
        #pragma unroll
        for (int i = 0; i < 9; ++i) w3v[i] = w3pk[g * 9 + i];
        #pragma unroll
        for (int r = 0; r < 5; ++r) {
            const unsigned* p = &tile[gi][yy + r][x0];
            unsigned win[12];
            *(f32x4*)win = *(const f32x4*)p;
            *(f32x4*)(win + 4) = *(const f32x4*)(p + 4);
            *(f32x4*)(win + 8) = *(const f32x4*)(p + 8);
            #pragma unroll
            for (int dx = 0; dx < 5; ++dx)
                #pragma unroll
                for (int j = 0; j < 8; ++j)
                    a5[gi][j] = dot2acc(win[j + dx], w5v[r * 5 + dx], a5[gi][j]);
            if (r >= 1 && r <= 3) {
                #pragma unroll
                for (int dx = 0; dx < 3; ++dx)
                    #pragma unroll
                    for (int j = 0; j < 8; ++j)
                        a3[gi][j] = dot2acc(win[j + dx + 1], w3v[(r - 1) * 3 + dx], a3[gi][j]);
            }
        }
    }
    long prow = (long)(y0 + yy) * WW + x0;
    #pragma unroll
    for (int gi = 0; gi < 2; ++gi) {
        int g = 2 * gp + gi;
        uint4 v3, v5;
        v3.x = packbf(a3[gi][0], a3[gi][1]);
        v3.y = packbf(a3[gi][2], a3[gi][3]);
        v3.z = packbf(a3[gi][4], a3[gi][5]);
        v3.w = packbf(a3[gi][6], a3[gi][7]);
        v5.x = packbf(a5[gi][0], a5[gi][1]);
        v5.y = packbf(a5[gi][2], a5[gi][3]);
        v5.z = packbf(a5[gi][4], a5[gi][5]);
        v5.w = packbf(a5[gi][6], a5[gi][7]);
        unsigned short* d3 = (g < s3) ? r3a + (long)b * st3a + (long)g * HW
                                      : r3b + (long)b * st3b + (long)(g - s3) * HW;
        unsigned short* d5 = (g < s5) ? r5a + (long)b * st5a + (long)g * HW
                                      : r5b + (long)b * st5b + (long)(g - s5) * HW;
        *(uint4*)(d3 + prow) = v3;
        *(uint4*)(d5 + prow) = v5;
    }
}

// ---------------- Gram + norms, 3 MFMAs per iter (S, q.q^T diag, k.k^T diag)
__global__ __launch_bounds__(64) void gram_mfma(
    const unsigned short* __restrict__ q,  // [NB][128][HW] bf16
    const unsigned short* __restrict__ k,
    float* __restrict__ gbuf)              // [NB*8][288]
{
    int bh = blockIdx.x, chunk = blockIdx.y;
    int b = bh >> 3, h = bh & 7;
    int l = threadIdx.x;
    int r = l & 15, koff = (l >> 4) * 8;
    const unsigned short* qrow = q + ((long)b * 128 + h * 16 + r) * HW;
    const unsigned short* krow = k + ((long)b * 128 + h * 16 + r) * HW;
    f32x4 accS = {0.f, 0.f, 0.f, 0.f};
    f32x4 accQ = {0.f, 0.f, 0.f, 0.f};
    f32x4 accK = {0.f, 0.f, 0.f, 0.f};
    int n0 = chunk * 256;
    for (int n = n0; n < n0 + 256; n += 32) {
        bf16x8 af = *(const bf16x8*)(qrow + n + koff);
        bf16x8 bf = *(const bf16x8*)(krow + n + koff);
        accS = __builtin_amdgcn_mfma_f32_16x16x32_bf16(af, bf, accS, 0, 0, 0);
        accQ = __builtin_amdgcn_mfma_f32_16x16x32_bf16(af, af, accQ, 0, 0, 0);
        accK = __builtin_amdgcn_mfma_f32_16x16x32_bf16(bf, bf, accK, 0, 0, 0);
    }
    float* gb = gbuf + bh * 288;
    #pragma unroll
    for (int reg = 0; reg < 4; ++reg) {
        int row = (l >> 4) * 4 + reg;
        atomicAdd(&gb[row * 16 + r], accS[reg]);
        if (row == r) {
            atomicAdd(&gb[256 + r], accQ[reg]);
            atomicAdd(&gb[272 + r], accK[reg]);
        }
    }
}

// ---------------- softmax + fold into packed bf16 proj weights
__global__ __launch_bounds__(256) void attn_fold(
    const float* __restrict__ gbuf, const float* __restrict__ temp,
    const float* __restrict__ projw,     // [128][256]
    unsigned* __restrict__ wallpk)       // [NB][128][128] u32 bf16-pairs
{
    int bh = blockIdx.x;
    int b = bh >> 3, h = bh & 7;
    const float* gb = gbuf + bh * 288;
    __shared__ float logit[16][16];
    __shared__ float A[16][16];
    int tid = threadIdx.x;
    int d = tid >> 4, e = tid & 15;
    {
        float nq = fmaxf(sqrtf(gb[256 + d]), 1e-12f);
        float nk = fmaxf(sqrtf(gb[272 + e]), 1e-12f);
        logit[d][e] = gb[d * 16 + e] / (nq * nk) * temp[h];
    }
    __syncthreads();
    float m = -1e30f;
    #pragma unroll
    for (int j = 0; j < 16; ++j) m = fmaxf(m, logit[d][j]);
    float ex = expf(logit[d][e] - m);
    A[d][e] = ex;
    __syncthreads();
    float sum = 0.f;
    #pragma unroll
    for (int j = 0; j < 16; ++j) sum += A[d][j];
    __syncthreads();
    A[d][e] = ex / sum;
    __syncthreads();
    int ep = tid & 7, co0 = tid >> 3;
    for (int co = co0; co < 128; co += 32) {
        float lo = 0.f, hi = 0.f;
        #pragma unroll
        for (int dd = 0; dd < 16; ++dd) {
            float pw = projw[co * 256 + h * 16 + dd];
            lo += pw * A[dd][2 * ep];
            hi += pw * A[dd][2 * ep + 1];
        }
        wallpk[((long)b * 128 + co) * 128 + h * 8 + ep] = packbf(lo, hi);
    }
    if (h == 0) {
        for (int idx = tid; idx < 128 * 64; idx += 256) {
            int co = idx >> 6, cp = idx & 63;
            wallpk[((long)b * 128 + co) * 128 + 64 + cp] =
                packbf(projw[co * 256 + 128 + 2 * cp], projw[co * 256 + 129 + 2 * cp]);
        }
    }
}

// ---------------- K6: out f32 = wallpk @ vy  (M=128, K=256, N-tile 64)
// 512 threads, 8 waves x 1 m-tile.
__global__ __launch_bounds__(512) void gemm_out(
    const unsigned* __restrict__ wpk,       // [NB][128][128] u32 (L2)
    const unsigned short* __restrict__ vy,  // [NB][256][HW] bf16
    float* __restrict__ out)                // [NB][128][HW]
{
    int b = blockIdx.z;
    int n0 = blockIdx.x * 64;
    const unsigned* wb = wpk + (long)b * 128 * 128;
    const unsigned short* vyb = vy + (long)b * 256 * HW;
    float* ob = out + (long)b * 128 * HW;
    __shared__ unsigned Bs[64][129];
    int tid = threadIdx.x;
    {   // stage 64 n x 128 kp: 512 threads, kp=tid>>2, 16 cols each
        int kp = tid >> 2, nh = (tid & 3) * 16;
        const unsigned short* s0 = vyb + (long)(2 * kp) * HW + n0 + nh;
        const unsigned short* s1 = s0 + HW;
        #pragma unroll
        for (int q4 = 0; q4 < 4; ++q4) {
            us4 lo = *(const us4*)(s0 + q4 * 4);
            us4 hi = *(const us4*)(s1 + q4 * 4);
            #pragma unroll
            for (int j = 0; j < 4; ++j)
                Bs[nh + q4 * 4 + j][kp] = (unsigned)lo[j] | ((unsigned)hi[j] << 16);
        }
    }
    __syncthreads();
    int w = tid >> 6, l = tid & 63;      // 8 waves, 1 m-tile each
    int lr = l & 15, lg = l >> 4;
    f32x4 acc[4] = {};
    #pragma unroll
    for (int kk = 0; kk < 8; ++kk) {
        int m = w * 16 + lr;
        bf16x8 af = *(const bf16x8*)(wb + (long)m * 128 + kk * 16 + lg * 4);
        #pragma unroll
        for (int ns = 0; ns < 4; ++ns) {
            bf16x8 bf = *(const bf16x8*)(&Bs[ns * 16 + lr][kk * 16 + lg * 4]);
            acc[ns] = __builtin_amdgcn_mfma_f32_16x16x32_bf16(af, bf, acc[ns], 0, 0, 0);
        }
    }
    #pragma unroll
    for (int ns = 0; ns < 4; ++ns)
        #pragma unroll
        for (int reg = 0; reg < 4; ++reg) {
            int m = w * 16 + lg * 4 + reg;
            ob[(long)m * HW + n0 + ns * 16 + lr] = acc[ns][reg];
        }
}

extern "C" void kernel_launch(void* const* d_in, const int* in_sizes, int n_in,
                              void* d_out, int out_size, void* d_ws, size_t ws_size,
                              hipStream_t stream) {
    const float* x      = (const float*)d_in[0];
    const float* pos_w  = (const float*)d_in[1];
    const float* pos_b  = (const float*)d_in[2];
    const float* qd3_w  = (const float*)d_in[3];
    const float* qd3_b  = (const float*)d_in[4];
    const float* qd5_w  = (const float*)d_in[5];
    const float* qd5_b  = (const float*)d_in[6];
    const float* temp   = (const float*)d_in[7];
    const float* d3_w   = (const float*)d_in[8];
    const float* d3_b   = (const float*)d_in[9];
    const float* d5_w   = (const float*)d_in[10];
    const float* d5_b   = (const float*)d_in[11];
    const float* proj_w = (const float*)d_in[12];
    float* out = (float*)d_out;

    // per-batch: tpk 12.58MB + (xpk|qb) 4.19 + kb 4.19 + vy 8.39 + wallpk 64K
    size_t perb = (size_t)HW * 1792 + 65536;
    size_t fixedb = 64UL * 288 * 4 + 384UL * 64 * 4 + 8704UL * 4;
    int NB = 8;
    while (NB > 1 && (size_t)NB * perb + fixedb > ws_size) NB >>= 1;

    char* base = (char*)d_ws;
    unsigned* tpk      = (unsigned*)base;       base += (size_t)NB * 192 * HW * 4;
    unsigned* xpk      = (unsigned*)base;                  // region A (aliased)
    unsigned short* qb = (unsigned short*)base; base += (size_t)NB * 128 * HW * 2;
    unsigned short* kb = (unsigned short*)base; base += (size_t)NB * 128 * HW * 2;
    unsigned short* vy = (unsigned short*)base; base += (size_t)NB * 256 * HW * 2;
    unsigned* wallpk   = (unsigned*)base;       base += (size_t)NB * 128 * 128 * 4;
    float* gram        = (float*)base;          base += 64UL * 288 * 4;
    unsigned* poswpk   = (unsigned*)base;       base += 384UL * 64 * 4;
    unsigned* cwpk     = (unsigned*)base;
    unsigned* qd3pk = cwpk;
    unsigned* qd5pk = cwpk + 192 * 9;
    unsigned* d3pk  = cwpk + 192 * 9 + 192 * 25;
    unsigned* d5pk  = cwpk + 192 * 9 + 192 * 25 + 64 * 9;

    packw<<<(384 * 64 + 255) / 256, 256, 0, stream>>>(pos_w, poswpk);
    packcw<<<(8704 + 255) / 256, 256, 0, stream>>>(qd3_w, qd5_w, d3_w, d5_w, cwpk);

    for (int b0 = 0; b0 < 8; b0 += NB) {
        const float* xb = x + (long)b0 * 128 * HW;
        float* outb = out + (long)b0 * 128 * HW;

        // t (pair-packed) = pos_w @ x + b ; also emits xpk (into qb region)
        gemm_t<<<dim3(HW / 64, 1, NB), 512, 0, stream>>>(poswpk, xb, pos_b, tpk, xpk);

        // convs on x (xpk): conv3 -> vy rows 128..191 ; conv5 -> rows 192..255
        // (must run BEFORE dualconv(t) overwrites the xpk/qb region)
        dualconv<<<dim3(4, 32, NB), 512, 0, stream>>>(
            xpk, 64, d3pk, d3_b, d5pk, d5_b,
            64, vy + 128L * HW, 256L * HW, vy + 128L * HW, 256L * HW,
            64, vy + 192L * HW, 256L * HW, vy + 192L * HW, 256L * HW);

        // convs on t: conv3: g<128 -> q(qb) ; g>=128 -> k rows 0..63
        //             conv5: g<64 -> k rows 64..127 ; g>=64 -> vy rows 0..127
        dualconv<<<dim3(4, 96, NB), 512, 0, stream>>>(
            tpk, 192, qd3pk, qd3_b, qd5pk, qd5_b,
            128, qb, 128L * HW, kb, 128L * HW,
            64, kb + 64L * HW, 128L * HW, vy, 256L * HW);

        zerok<<<(64 * 288 + 255) / 256, 256, 0, stream>>>(gram, 64 * 288);
        gram_mfma<<<dim3(NB * 8, 64), 64, 0, stream>>>(qb, kb, gram);
        attn_fold<<<NB * 8, 256, 0, stream>>>(gram, temp, proj_w, wallpk);

        gemm_out<<<dim3(HW / 64, 1, NB), 512, 0, stream>>>(wallpk, vy, outb);
    }
}